// Round 13
// baseline (54.085 us; speedup 1.0000x reference)
//
#include <hip/hip_runtime.h>
#include <math.h>

#define LL 4096
#define CC 128
#define SS 64
#define CLEN 32    // steps per chunk (wave)
#define GW 8       // chunks (waves) per group/block
#define NG 16      // groups; NG*GW*CLEN = LL
#define CS 8192    // CC*SS
#define LOG2E 1.44269504088896f

// ---------------- kernel 1: projections (B, Cm, dtT) + xT ----------------
// 256 blocks x 512 thr; block = 16 rows; thread = 2 rows x 4 cols.
// Same W/x traffic as the 256-thr version, 2x the resident waves per CU.
__global__ __launch_bounds__(512) void k_proj(
    const float* __restrict__ x,
    const float* __restrict__ Bk, const float* __restrict__ Bb,
    const float* __restrict__ Ck, const float* __restrict__ Cb,
    const float* __restrict__ Dk, const float* __restrict__ Db,
    float* __restrict__ Bmat, float* __restrict__ Cmat,
    float* __restrict__ DTmT, float* __restrict__ xT)
{
    __shared__ float xs[CC][20];   // transposed x tile [k][row]; 80B rows, 16B-aligned
    const int r0 = blockIdx.x * 16;
    const int t = threadIdx.x;
    {
        const int r = t >> 5, k4 = (t & 31) * 4;
        const float4 v = *(const float4*)&x[(r0 + r) * CC + k4];
        xs[k4+0][r] = v.x; xs[k4+1][r] = v.y; xs[k4+2][r] = v.z; xs[k4+3][r] = v.w;
    }
    __syncthreads();
    {   // emit x transposed [C][L]
        const int k = t >> 2, q = (t & 3) * 4;
        *(float4*)&xT[k * LL + r0 + q] = *(const float4*)&xs[k][q];
    }
    const int tc = t & 63, tr = t >> 6;        // tr = 0..7
    const int rb = r0 + 2 * tr;                // 2 rows per thread
    const float* Wb; int wstride, wo;
    if (tc < 16)      { Wb = Bk; wstride = SS; wo = 4 * tc; }
    else if (tc < 32) { Wb = Ck; wstride = SS; wo = 4 * tc - 64; }
    else              { Wb = Dk; wstride = CC; wo = 4 * tc - 128; }
    float acc[2][4];
#pragma unroll
    for (int r = 0; r < 2; ++r)
#pragma unroll
        for (int j = 0; j < 4; ++j) acc[r][j] = 0.0f;
    for (int k = 0; k < CC; ++k) {
        const float4 wq = *(const float4*)(Wb + k * wstride + wo);
        const float2 xq = *(const float2*)&xs[k][2 * tr];
        const float wv[4] = {wq.x, wq.y, wq.z, wq.w};
        const float xv[2] = {xq.x, xq.y};
#pragma unroll
        for (int r = 0; r < 2; ++r)
#pragma unroll
            for (int j = 0; j < 4; ++j) acc[r][j] = fmaf(xv[r], wv[j], acc[r][j]);
    }
    if (tc < 32) {
        const float* bb = (tc < 16) ? Bb : Cb;
        const float add = (tc < 16) ? 1.0f : 0.0f;
        float bias[4];
#pragma unroll
        for (int j = 0; j < 4; ++j) bias[j] = add + bb[wo + j];
        float* dst = (tc < 16) ? Bmat : Cmat;
#pragma unroll
        for (int r = 0; r < 2; ++r) {
            const float4 o = make_float4(acc[r][0] + bias[0], acc[r][1] + bias[1],
                                         acc[r][2] + bias[2], acc[r][3] + bias[3]);
            *(float4*)&dst[(rb + r) * SS + wo] = o;
        }
    } else {
#pragma unroll
        for (int j = 0; j < 4; ++j) {
            const float bj = Db[wo + j] + 0.000244140625f;
            float sp[2];
#pragma unroll
            for (int r = 0; r < 2; ++r) {
                const float z = acc[r][j] + bj;
                sp[r] = fmaxf(z, 0.0f) + log1pf(__expf(-fabsf(z)));  // stable softplus
            }
            *(float2*)&DTmT[(wo + j) * LL + rb] = make_float2(sp[0], sp[1]);
        }
    }
}

// ------- kernel 2: group aggregates (R12 verbatim) -------
// block = (c, g): 2048 blocks x 512 thr = 8 waves = 8 chunks of group g. lane = s.
__global__ __launch_bounds__(512, 4) void k_sweep1(
    const float* __restrict__ xT, const float* __restrict__ A_log,
    const float* __restrict__ Bmat, const float* __restrict__ DTmT,
    float2* __restrict__ GaGu)
{
    __shared__ float2 agg[GW][SS];
    const int lane = threadIdx.x & 63;
    const int w = __builtin_amdgcn_readfirstlane(threadIdx.x >> 6);
    const int c = blockIdx.x >> 4;          // SGPR
    const int g = blockIdx.x & (NG - 1);    // SGPR
    const int j = c * SS + lane;
    const float A = -__expf(A_log[j]);
    const float A2 = A * LOG2E;             // At = 2^(A2*dt)
    const float invA = 1.0f / A;
    const int l0 = (g * GW + w) * CLEN;
    const float* dtp = DTmT + c * LL + l0;  // uniform + contiguous -> s_load batches
    const float* xp  = xT   + c * LL + l0;
    const float* Bp  = Bmat + l0 * SS + lane;
    float ap = 1.0f, uc = 0.0f;
#pragma unroll
    for (int i = 0; i < CLEN; ++i) {
        const float At = __builtin_amdgcn_exp2f(A2 * dtp[i]);
        const float u  = (At - 1.0f) * invA * (Bp[i * SS] * xp[i]);
        ap *= At;
        uc = fmaf(At, uc, u);
    }
    agg[w][lane] = make_float2(ap, uc);
    __syncthreads();
    if (w == 0) {   // compose 8 chunks in time order -> group aggregate
        float ga = 1.0f, gu = 0.0f;
#pragma unroll
        for (int k = 0; k < GW; ++k) {
            const float2 t = agg[k][lane];
            gu = fmaf(t.x, gu, t.y);
            ga *= t.x;
        }
        GaGu[g * CS + j] = make_float2(ga, gu);
    }
}

// ------- kernel 3: wave0-prologue + reg-cached rewalk + emit -------
// __launch_bounds__(512,2): 256-VGPR budget so at[]/uu[] truly live in regs.
__global__ __launch_bounds__(512, 2) void k_emit(
    const float* __restrict__ xT, const float* __restrict__ A_log,
    const float* __restrict__ Bmat, const float* __restrict__ Cmat,
    const float* __restrict__ DTmT,
    const float2* __restrict__ GaGu,
    float* __restrict__ y)
{
    __shared__ float2 agg[GW][SS];
    __shared__ float hgs[SS];
    const int lane = threadIdx.x & 63;
    const int w = __builtin_amdgcn_readfirstlane(threadIdx.x >> 6);
    const int c = blockIdx.x >> 4;          // SGPR
    const int g = blockIdx.x & (NG - 1);    // SGPR
    const int j = c * SS + lane;
    const float A = -__expf(A_log[j]);
    const float A2 = A * LOG2E;
    const float invA = 1.0f / A;
    // cross-group exclusive prefix: wave 0 only (identical across waves)
    if (w == 0) {
        float hg = 0.0f;
        float2 ggr[NG - 1];
#pragma unroll
        for (int gg = 0; gg < NG - 1; ++gg) ggr[gg] = GaGu[gg * CS + j];
#pragma unroll
        for (int gg = 0; gg < NG - 1; ++gg)
            hg = (gg < g) ? fmaf(ggr[gg].x, hg, ggr[gg].y) : hg;
        hgs[lane] = hg;
    }
    const int l0 = (g * GW + w) * CLEN;
    const float* dtp = DTmT + c * LL + l0;
    const float* xp  = xT   + c * LL + l0;
    const float* Bp  = Bmat + l0 * SS + lane;
    const float* Cp  = Cmat + l0 * SS + lane;
    // pass 1: chunk aggregate, caching at[] / uu[] in registers
    float at[CLEN], uu[CLEN];
    {
        float ap = 1.0f, uc = 0.0f;
#pragma unroll
        for (int i = 0; i < CLEN; ++i) {
            at[i] = __builtin_amdgcn_exp2f(A2 * dtp[i]);
            uu[i] = (at[i] - 1.0f) * invA * (Bp[i * SS] * xp[i]);
            ap *= at[i];
            uc = fmaf(at[i], uc, uu[i]);
        }
        agg[w][lane] = make_float2(ap, uc);
    }
    __syncthreads();
    const float hg = hgs[lane];
    // in-block exclusive prefix over chunks 0..w-1 (trip count wave-uniform)
    float ea = 1.0f, eu = 0.0f;
    for (int k = 0; k < w; ++k) {
        const float2 t = agg[k][lane];
        eu = fmaf(t.x, eu, t.y);
        ea *= t.x;
    }
    float h = fmaf(ea, hg, eu);
    // pass 2: rewalk from registers; uu[] becomes p[]
#pragma unroll
    for (int i = 0; i < CLEN; ++i) {
        h = fmaf(at[i], h, uu[i]);
        uu[i] = Cp[i * SS] * h;
    }
    // 32-row x 64-lane register-halving transpose-reduce
#pragma unroll
    for (int k = 0; k < 5; ++k) {
        const int d = 1 << k;
        const bool hi = (lane & d) != 0;
#pragma unroll
        for (int i2 = 0; i2 < (CLEN >> (k + 1)); ++i2) {
            const float a = uu[2 * i2], b = uu[2 * i2 + 1];
            const float send = hi ? a : b;
            const float t = __shfl_xor(send, d, 64);
            uu[i2] = (hi ? b : a) + t;
        }
    }
    const float t = __shfl_xor(uu[0], 32, 64);
    const float yv = uu[0] + t;
    if (lane < 32) y[(l0 + lane) * CC + c] = yv;
}

extern "C" void kernel_launch(void* const* d_in, const int* in_sizes, int n_in,
                              void* d_out, int out_size, void* d_ws, size_t ws_size,
                              hipStream_t stream)
{
    const float* x  = (const float*)d_in[0];
    const float* Al = (const float*)d_in[1];
    const float* Bk = (const float*)d_in[2];
    const float* Bb = (const float*)d_in[3];
    const float* Ck = (const float*)d_in[4];
    const float* Cb = (const float*)d_in[5];
    const float* Dk = (const float*)d_in[6];
    const float* Db = (const float*)d_in[7];
    float* y  = (float*)d_out;
    float* ws = (float*)d_ws;

    float*  Bmat = ws;                        // [L][S]   1 MB
    float*  Cmat = Bmat + LL * SS;            // [L][S]   1 MB
    float*  DTmT = Cmat + LL * SS;            // [C][L]   2 MB
    float*  xT   = DTmT + CC * LL;            // [C][L]   2 MB
    float2* GaGu = (float2*)(xT + CC * LL);   // [NG][CS] 1 MB

    k_proj  <<<LL / 16, 512, 0, stream>>>(x, Bk, Bb, Ck, Cb, Dk, Db, Bmat, Cmat, DTmT, xT);
    k_sweep1<<<CC * NG, 512, 0, stream>>>(xT, Al, Bmat, DTmT, GaGu);
    k_emit  <<<CC * NG, 512, 0, stream>>>(xT, Al, Bmat, Cmat, DTmT, GaGu, y);
}

// Round 14
// 51.682 us; speedup vs baseline: 1.0465x; 1.0465x over previous
//
#include <hip/hip_runtime.h>
#include <math.h>

#define LL 4096
#define CC 128
#define SS 64
#define CLEN 32    // steps per chunk (wave)
#define GW 8       // chunks (waves) per group/block
#define NG 16      // groups; NG*GW*CLEN = LL
#define CS 8192    // CC*SS
#define LOG2E 1.44269504088896f

// ---------------- kernel 1: projections (B, Cm, dtT) + xT ----------------
// 1024 blocks x 64 thr (1 wave). block = (stripe of 16 rows, col-group cg):
//   cg0 -> Bmat cols 0..63, cg1 -> Cmat cols 0..63, cg2/3 -> dt cols 0..63/64..127.
// thread = 4 rows x 4 cols; k-loop in 8-chunks, all operands in registers (no LDS).
__global__ __launch_bounds__(64) void k_proj(
    const float* __restrict__ x,
    const float* __restrict__ Bk, const float* __restrict__ Bb,
    const float* __restrict__ Ck, const float* __restrict__ Cb,
    const float* __restrict__ Dk, const float* __restrict__ Db,
    float* __restrict__ Bmat, float* __restrict__ Cmat,
    float* __restrict__ DTmT, float* __restrict__ xT)
{
    const int b = blockIdx.x;
    const int stripe = b >> 2, cg = b & 3;
    const int r0 = stripe * 16;
    const int lane = threadIdx.x;
    const int cq = lane & 15, rq = lane >> 4;
    const int rb = r0 + 4 * rq;
    const float* W; int wstr, wo;
    if (cg == 0)      { W = Bk; wstr = SS; wo = 4 * cq; }
    else if (cg == 1) { W = Ck; wstr = SS; wo = 4 * cq; }
    else if (cg == 2) { W = Dk; wstr = CC; wo = 4 * cq; }
    else              { W = Dk; wstr = CC; wo = 64 + 4 * cq; }

    float acc[4][4];
#pragma unroll
    for (int r = 0; r < 4; ++r)
#pragma unroll
        for (int j = 0; j < 4; ++j) acc[r][j] = 0.0f;

    for (int it = 0; it < 16; ++it) {
        const int k8 = it * 8;
        float4 wv[8];
#pragma unroll
        for (int i = 0; i < 8; ++i)
            wv[i] = *(const float4*)(W + (k8 + i) * wstr + wo);
        float xf[4][8];
#pragma unroll
        for (int r = 0; r < 4; ++r) {
            const float4 a  = *(const float4*)&x[(rb + r) * CC + k8];
            const float4 b2 = *(const float4*)&x[(rb + r) * CC + k8 + 4];
            xf[r][0] = a.x;  xf[r][1] = a.y;  xf[r][2] = a.z;  xf[r][3] = a.w;
            xf[r][4] = b2.x; xf[r][5] = b2.y; xf[r][6] = b2.z; xf[r][7] = b2.w;
        }
#pragma unroll
        for (int i = 0; i < 8; ++i) {
            const float4 wq = wv[i];
#pragma unroll
            for (int r = 0; r < 4; ++r) {
                acc[r][0] = fmaf(xf[r][i], wq.x, acc[r][0]);
                acc[r][1] = fmaf(xf[r][i], wq.y, acc[r][1]);
                acc[r][2] = fmaf(xf[r][i], wq.z, acc[r][2]);
                acc[r][3] = fmaf(xf[r][i], wq.w, acc[r][3]);
            }
        }
        // cg0 threads with cq==it emit x transposed for this k-chunk:
        // 4 active lanes (rq 0..3) x float4 = rows r0..r0+15 of xT[k][*].
        if (cg == 0 && cq == it) {
#pragma unroll
            for (int i = 0; i < 8; ++i) {
                *(float4*)&xT[(k8 + i) * LL + rb] =
                    make_float4(xf[0][i], xf[1][i], xf[2][i], xf[3][i]);
            }
        }
    }

    if (cg < 2) {
        const float* bb = (cg == 0) ? Bb : Cb;
        const float add = (cg == 0) ? 1.0f : 0.0f;
        float* dst = (cg == 0) ? Bmat : Cmat;
        float bias[4];
#pragma unroll
        for (int j = 0; j < 4; ++j) bias[j] = add + bb[wo + j];
#pragma unroll
        for (int r = 0; r < 4; ++r) {
            const float4 o = make_float4(acc[r][0] + bias[0], acc[r][1] + bias[1],
                                         acc[r][2] + bias[2], acc[r][3] + bias[3]);
            *(float4*)&dst[(rb + r) * SS + wo] = o;
        }
    } else {
#pragma unroll
        for (int j = 0; j < 4; ++j) {
            const float bj = Db[wo + j] + 0.000244140625f;
            float sp[4];
#pragma unroll
            for (int r = 0; r < 4; ++r) {
                const float z = acc[r][j] + bj;
                sp[r] = fmaxf(z, 0.0f) + log1pf(__expf(-fabsf(z)));  // stable softplus
            }
            *(float4*)&DTmT[(wo + j) * LL + rb] = make_float4(sp[0], sp[1], sp[2], sp[3]);
        }
    }
}

// ------- kernel 2: group aggregates (R12 verbatim) -------
// block = (c, g): 2048 blocks x 512 thr = 8 waves = 8 chunks of group g. lane = s.
__global__ __launch_bounds__(512, 4) void k_sweep1(
    const float* __restrict__ xT, const float* __restrict__ A_log,
    const float* __restrict__ Bmat, const float* __restrict__ DTmT,
    float2* __restrict__ GaGu)
{
    __shared__ float2 agg[GW][SS];
    const int lane = threadIdx.x & 63;
    const int w = __builtin_amdgcn_readfirstlane(threadIdx.x >> 6);
    const int c = blockIdx.x >> 4;          // SGPR
    const int g = blockIdx.x & (NG - 1);    // SGPR
    const int j = c * SS + lane;
    const float A = -__expf(A_log[j]);
    const float A2 = A * LOG2E;             // At = 2^(A2*dt)
    const float invA = 1.0f / A;
    const int l0 = (g * GW + w) * CLEN;
    const float* dtp = DTmT + c * LL + l0;  // uniform + contiguous -> s_load batches
    const float* xp  = xT   + c * LL + l0;
    const float* Bp  = Bmat + l0 * SS + lane;
    float ap = 1.0f, uc = 0.0f;
#pragma unroll
    for (int i = 0; i < CLEN; ++i) {
        const float At = __builtin_amdgcn_exp2f(A2 * dtp[i]);
        const float u  = (At - 1.0f) * invA * (Bp[i * SS] * xp[i]);
        ap *= At;
        uc = fmaf(At, uc, u);
    }
    agg[w][lane] = make_float2(ap, uc);
    __syncthreads();
    if (w == 0) {   // compose 8 chunks in time order -> group aggregate
        float ga = 1.0f, gu = 0.0f;
#pragma unroll
        for (int k = 0; k < GW; ++k) {
            const float2 t = agg[k][lane];
            gu = fmaf(t.x, gu, t.y);
            ga *= t.x;
        }
        GaGu[g * CS + j] = make_float2(ga, gu);
    }
}

// ------- kernel 3: wave0-prologue + reg-cached rewalk + emit (R12 verbatim) --
__global__ __launch_bounds__(512, 4) void k_emit(
    const float* __restrict__ xT, const float* __restrict__ A_log,
    const float* __restrict__ Bmat, const float* __restrict__ Cmat,
    const float* __restrict__ DTmT,
    const float2* __restrict__ GaGu,
    float* __restrict__ y)
{
    __shared__ float2 agg[GW][SS];
    __shared__ float hgs[SS];
    const int lane = threadIdx.x & 63;
    const int w = __builtin_amdgcn_readfirstlane(threadIdx.x >> 6);
    const int c = blockIdx.x >> 4;          // SGPR
    const int g = blockIdx.x & (NG - 1);    // SGPR
    const int j = c * SS + lane;
    const float A = -__expf(A_log[j]);
    const float A2 = A * LOG2E;
    const float invA = 1.0f / A;
    // cross-group exclusive prefix: wave 0 only (identical across waves)
    if (w == 0) {
        float hg = 0.0f;
        float2 ggr[NG - 1];
#pragma unroll
        for (int gg = 0; gg < NG - 1; ++gg) ggr[gg] = GaGu[gg * CS + j];
#pragma unroll
        for (int gg = 0; gg < NG - 1; ++gg)
            hg = (gg < g) ? fmaf(ggr[gg].x, hg, ggr[gg].y) : hg;
        hgs[lane] = hg;
    }
    const int l0 = (g * GW + w) * CLEN;
    const float* dtp = DTmT + c * LL + l0;
    const float* xp  = xT   + c * LL + l0;
    const float* Bp  = Bmat + l0 * SS + lane;
    const float* Cp  = Cmat + l0 * SS + lane;
    // pass 1: chunk aggregate, caching at[] / uu[] in registers
    float at[CLEN], uu[CLEN];
    {
        float ap = 1.0f, uc = 0.0f;
#pragma unroll
        for (int i = 0; i < CLEN; ++i) {
            at[i] = __builtin_amdgcn_exp2f(A2 * dtp[i]);
            uu[i] = (at[i] - 1.0f) * invA * (Bp[i * SS] * xp[i]);
            ap *= at[i];
            uc = fmaf(at[i], uc, uu[i]);
        }
        agg[w][lane] = make_float2(ap, uc);
    }
    __syncthreads();
    const float hg = hgs[lane];
    // in-block exclusive prefix over chunks 0..w-1 (trip count wave-uniform)
    float ea = 1.0f, eu = 0.0f;
    for (int k = 0; k < w; ++k) {
        const float2 t = agg[k][lane];
        eu = fmaf(t.x, eu, t.y);
        ea *= t.x;
    }
    float h = fmaf(ea, hg, eu);
    // pass 2: rewalk from registers; uu[] becomes p[]
#pragma unroll
    for (int i = 0; i < CLEN; ++i) {
        h = fmaf(at[i], h, uu[i]);
        uu[i] = Cp[i * SS] * h;
    }
    // 32-row x 64-lane register-halving transpose-reduce
#pragma unroll
    for (int k = 0; k < 5; ++k) {
        const int d = 1 << k;
        const bool hi = (lane & d) != 0;
#pragma unroll
        for (int i2 = 0; i2 < (CLEN >> (k + 1)); ++i2) {
            const float a = uu[2 * i2], b = uu[2 * i2 + 1];
            const float send = hi ? a : b;
            const float t = __shfl_xor(send, d, 64);
            uu[i2] = (hi ? b : a) + t;
        }
    }
    const float t = __shfl_xor(uu[0], 32, 64);
    const float yv = uu[0] + t;
    if (lane < 32) y[(l0 + lane) * CC + c] = yv;
}

extern "C" void kernel_launch(void* const* d_in, const int* in_sizes, int n_in,
                              void* d_out, int out_size, void* d_ws, size_t ws_size,
                              hipStream_t stream)
{
    const float* x  = (const float*)d_in[0];
    const float* Al = (const float*)d_in[1];
    const float* Bk = (const float*)d_in[2];
    const float* Bb = (const float*)d_in[3];
    const float* Ck = (const float*)d_in[4];
    const float* Cb = (const float*)d_in[5];
    const float* Dk = (const float*)d_in[6];
    const float* Db = (const float*)d_in[7];
    float* y  = (float*)d_out;
    float* ws = (float*)d_ws;

    float*  Bmat = ws;                        // [L][S]   1 MB
    float*  Cmat = Bmat + LL * SS;            // [L][S]   1 MB
    float*  DTmT = Cmat + LL * SS;            // [C][L]   2 MB
    float*  xT   = DTmT + CC * LL;            // [C][L]   2 MB
    float2* GaGu = (float2*)(xT + CC * LL);   // [NG][CS] 1 MB

    k_proj  <<<1024,    64,  0, stream>>>(x, Bk, Bb, Ck, Cb, Dk, Db, Bmat, Cmat, DTmT, xT);
    k_sweep1<<<CC * NG, 512, 0, stream>>>(xT, Al, Bmat, DTmT, GaGu);
    k_emit  <<<CC * NG, 512, 0, stream>>>(xT, Al, Bmat, Cmat, DTmT, GaGu, y);
}

// Round 15
// 47.723 us; speedup vs baseline: 1.1333x; 1.0830x over previous
//
#include <hip/hip_runtime.h>
#include <math.h>

#define LL 4096
#define CC 128
#define SS 64
#define CLEN 32    // steps per chunk (wave)
#define GW 8       // chunks (waves) per group/block
#define NG 16      // groups; NG*GW*CLEN = LL
#define CS 8192    // CC*SS
#define LOG2E 1.44269504088896f

// ---------------- kernel 1: projections (B, Cm, dtT) + xT ----------------
// 512 blocks x 256 thr; block = (stripe of 16 rows) x (half h: 0 = B+C, 1 = dt).
// thread = 2 rows x 4 cols; k-loop unrolled by 8 with batched W loads.
__global__ __launch_bounds__(256) void k_proj(
    const float* __restrict__ x,
    const float* __restrict__ Bk, const float* __restrict__ Bb,
    const float* __restrict__ Ck, const float* __restrict__ Cb,
    const float* __restrict__ Dk, const float* __restrict__ Db,
    float* __restrict__ Bmat, float* __restrict__ Cmat,
    float* __restrict__ DTmT, float* __restrict__ xT)
{
    __shared__ float xs[CC][20];   // transposed x tile [k][row]; 80B rows
    const int stripe = blockIdx.x >> 1;
    const int h = blockIdx.x & 1;
    const int r0 = stripe * 16;
    const int t = threadIdx.x;
    {
        const int r = t >> 4, k8 = (t & 15) * 8;
        const float4 v0 = *(const float4*)&x[(r0 + r) * CC + k8];
        const float4 v1 = *(const float4*)&x[(r0 + r) * CC + k8 + 4];
        xs[k8+0][r] = v0.x; xs[k8+1][r] = v0.y; xs[k8+2][r] = v0.z; xs[k8+3][r] = v0.w;
        xs[k8+4][r] = v1.x; xs[k8+5][r] = v1.y; xs[k8+6][r] = v1.z; xs[k8+7][r] = v1.w;
    }
    __syncthreads();
    const int tc = t & 31;           // col-quad within half (cols 4tc..4tc+3)
    const int tr = t >> 5;           // row-pair (0..7): rows rb, rb+1
    const int rb = r0 + 2 * tr;
    const float* W; int wstr, wo;
    bool isB = false;
    if (h == 0) {
        isB = (tc < 16);
        if (isB) { W = Bk; wstr = SS; wo = 4 * tc; }
        else     { W = Ck; wstr = SS; wo = 4 * tc - 64; }
    } else       { W = Dk; wstr = CC; wo = 4 * tc; }

    float acc[2][4];
#pragma unroll
    for (int r = 0; r < 2; ++r)
#pragma unroll
        for (int j = 0; j < 4; ++j) acc[r][j] = 0.0f;

    for (int k0 = 0; k0 < CC; k0 += 8) {
        float4 wq[8];
#pragma unroll
        for (int i = 0; i < 8; ++i)
            wq[i] = *(const float4*)(W + (k0 + i) * wstr + wo);   // 8 loads in flight
#pragma unroll
        for (int i = 0; i < 8; ++i) {
            const float2 xq = *(const float2*)&xs[k0 + i][2 * tr];
            acc[0][0] = fmaf(xq.x, wq[i].x, acc[0][0]);
            acc[0][1] = fmaf(xq.x, wq[i].y, acc[0][1]);
            acc[0][2] = fmaf(xq.x, wq[i].z, acc[0][2]);
            acc[0][3] = fmaf(xq.x, wq[i].w, acc[0][3]);
            acc[1][0] = fmaf(xq.y, wq[i].x, acc[1][0]);
            acc[1][1] = fmaf(xq.y, wq[i].y, acc[1][1]);
            acc[1][2] = fmaf(xq.y, wq[i].z, acc[1][2]);
            acc[1][3] = fmaf(xq.y, wq[i].w, acc[1][3]);
        }
    }

    if (h == 0) {
        const float* bb = isB ? Bb : Cb;
        const float add = isB ? 1.0f : 0.0f;
        float* dst = isB ? Bmat : Cmat;
        float bias[4];
#pragma unroll
        for (int j = 0; j < 4; ++j) bias[j] = add + bb[wo + j];
#pragma unroll
        for (int r = 0; r < 2; ++r) {
            const float4 o = make_float4(acc[r][0] + bias[0], acc[r][1] + bias[1],
                                         acc[r][2] + bias[2], acc[r][3] + bias[3]);
            *(float4*)&dst[(rb + r) * SS + wo] = o;
        }
    } else {
        // dt: softplus + transposed store
#pragma unroll
        for (int j = 0; j < 4; ++j) {
            const float bj = Db[wo + j] + 0.000244140625f;
            float sp[2];
#pragma unroll
            for (int r = 0; r < 2; ++r) {
                const float z = acc[r][j] + bj;
                sp[r] = fmaxf(z, 0.0f) + log1pf(__expf(-fabsf(z)));  // stable softplus
            }
            *(float2*)&DTmT[(wo + j) * LL + rb] = make_float2(sp[0], sp[1]);
        }
        // emit x transposed [C][L] (tile already transposed in LDS)
        const int k = t >> 1, half8 = (t & 1) * 8;
        const float4 a = *(const float4*)&xs[k][half8];
        const float4 b = *(const float4*)&xs[k][half8 + 4];
        *(float4*)&xT[k * LL + r0 + half8]     = a;
        *(float4*)&xT[k * LL + r0 + half8 + 4] = b;
    }
}

// ------- kernel 2: group aggregates (R12 verbatim) -------
// block = (c, g): 2048 blocks x 512 thr = 8 waves = 8 chunks of group g. lane = s.
__global__ __launch_bounds__(512, 4) void k_sweep1(
    const float* __restrict__ xT, const float* __restrict__ A_log,
    const float* __restrict__ Bmat, const float* __restrict__ DTmT,
    float2* __restrict__ GaGu)
{
    __shared__ float2 agg[GW][SS];
    const int lane = threadIdx.x & 63;
    const int w = __builtin_amdgcn_readfirstlane(threadIdx.x >> 6);
    const int c = blockIdx.x >> 4;          // SGPR
    const int g = blockIdx.x & (NG - 1);    // SGPR
    const int j = c * SS + lane;
    const float A = -__expf(A_log[j]);
    const float A2 = A * LOG2E;             // At = 2^(A2*dt)
    const float invA = 1.0f / A;
    const int l0 = (g * GW + w) * CLEN;
    const float* dtp = DTmT + c * LL + l0;  // uniform + contiguous -> s_load batches
    const float* xp  = xT   + c * LL + l0;
    const float* Bp  = Bmat + l0 * SS + lane;
    float ap = 1.0f, uc = 0.0f;
#pragma unroll
    for (int i = 0; i < CLEN; ++i) {
        const float At = __builtin_amdgcn_exp2f(A2 * dtp[i]);
        const float u  = (At - 1.0f) * invA * (Bp[i * SS] * xp[i]);
        ap *= At;
        uc = fmaf(At, uc, u);
    }
    agg[w][lane] = make_float2(ap, uc);
    __syncthreads();
    if (w == 0) {   // compose 8 chunks in time order -> group aggregate
        float ga = 1.0f, gu = 0.0f;
#pragma unroll
        for (int k = 0; k < GW; ++k) {
            const float2 t = agg[k][lane];
            gu = fmaf(t.x, gu, t.y);
            ga *= t.x;
        }
        GaGu[g * CS + j] = make_float2(ga, gu);
    }
}

// ------- kernel 3: wave0-prologue + reg-cached rewalk + emit (R12 verbatim) --
__global__ __launch_bounds__(512, 4) void k_emit(
    const float* __restrict__ xT, const float* __restrict__ A_log,
    const float* __restrict__ Bmat, const float* __restrict__ Cmat,
    const float* __restrict__ DTmT,
    const float2* __restrict__ GaGu,
    float* __restrict__ y)
{
    __shared__ float2 agg[GW][SS];
    __shared__ float hgs[SS];
    const int lane = threadIdx.x & 63;
    const int w = __builtin_amdgcn_readfirstlane(threadIdx.x >> 6);
    const int c = blockIdx.x >> 4;          // SGPR
    const int g = blockIdx.x & (NG - 1);    // SGPR
    const int j = c * SS + lane;
    const float A = -__expf(A_log[j]);
    const float A2 = A * LOG2E;
    const float invA = 1.0f / A;
    // cross-group exclusive prefix: wave 0 only (identical across waves)
    if (w == 0) {
        float hg = 0.0f;
        float2 ggr[NG - 1];
#pragma unroll
        for (int gg = 0; gg < NG - 1; ++gg) ggr[gg] = GaGu[gg * CS + j];
#pragma unroll
        for (int gg = 0; gg < NG - 1; ++gg)
            hg = (gg < g) ? fmaf(ggr[gg].x, hg, ggr[gg].y) : hg;
        hgs[lane] = hg;
    }
    const int l0 = (g * GW + w) * CLEN;
    const float* dtp = DTmT + c * LL + l0;
    const float* xp  = xT   + c * LL + l0;
    const float* Bp  = Bmat + l0 * SS + lane;
    const float* Cp  = Cmat + l0 * SS + lane;
    // pass 1: chunk aggregate, caching at[] / uu[] in registers
    float at[CLEN], uu[CLEN];
    {
        float ap = 1.0f, uc = 0.0f;
#pragma unroll
        for (int i = 0; i < CLEN; ++i) {
            at[i] = __builtin_amdgcn_exp2f(A2 * dtp[i]);
            uu[i] = (at[i] - 1.0f) * invA * (Bp[i * SS] * xp[i]);
            ap *= at[i];
            uc = fmaf(at[i], uc, uu[i]);
        }
        agg[w][lane] = make_float2(ap, uc);
    }
    __syncthreads();
    const float hg = hgs[lane];
    // in-block exclusive prefix over chunks 0..w-1 (trip count wave-uniform)
    float ea = 1.0f, eu = 0.0f;
    for (int k = 0; k < w; ++k) {
        const float2 t = agg[k][lane];
        eu = fmaf(t.x, eu, t.y);
        ea *= t.x;
    }
    float h = fmaf(ea, hg, eu);
    // pass 2: rewalk from registers; uu[] becomes p[]
#pragma unroll
    for (int i = 0; i < CLEN; ++i) {
        h = fmaf(at[i], h, uu[i]);
        uu[i] = Cp[i * SS] * h;
    }
    // 32-row x 64-lane register-halving transpose-reduce
#pragma unroll
    for (int k = 0; k < 5; ++k) {
        const int d = 1 << k;
        const bool hi = (lane & d) != 0;
#pragma unroll
        for (int i2 = 0; i2 < (CLEN >> (k + 1)); ++i2) {
            const float a = uu[2 * i2], b = uu[2 * i2 + 1];
            const float send = hi ? a : b;
            const float t = __shfl_xor(send, d, 64);
            uu[i2] = (hi ? b : a) + t;
        }
    }
    const float t = __shfl_xor(uu[0], 32, 64);
    const float yv = uu[0] + t;
    if (lane < 32) y[(l0 + lane) * CC + c] = yv;
}

extern "C" void kernel_launch(void* const* d_in, const int* in_sizes, int n_in,
                              void* d_out, int out_size, void* d_ws, size_t ws_size,
                              hipStream_t stream)
{
    const float* x  = (const float*)d_in[0];
    const float* Al = (const float*)d_in[1];
    const float* Bk = (const float*)d_in[2];
    const float* Bb = (const float*)d_in[3];
    const float* Ck = (const float*)d_in[4];
    const float* Cb = (const float*)d_in[5];
    const float* Dk = (const float*)d_in[6];
    const float* Db = (const float*)d_in[7];
    float* y  = (float*)d_out;
    float* ws = (float*)d_ws;

    float*  Bmat = ws;                        // [L][S]   1 MB
    float*  Cmat = Bmat + LL * SS;            // [L][S]   1 MB
    float*  DTmT = Cmat + LL * SS;            // [C][L]   2 MB
    float*  xT   = DTmT + CC * LL;            // [C][L]   2 MB
    float2* GaGu = (float2*)(xT + CC * LL);   // [NG][CS] 1 MB

    k_proj  <<<2 * (LL / 16), 256, 0, stream>>>(x, Bk, Bb, Ck, Cb, Dk, Db, Bmat, Cmat, DTmT, xT);
    k_sweep1<<<CC * NG,       512, 0, stream>>>(xT, Al, Bmat, DTmT, GaGu);
    k_emit  <<<CC * NG,       512, 0, stream>>>(xT, Al, Bmat, Cmat, DTmT, GaGu, y);
}

// Round 16
// 46.937 us; speedup vs baseline: 1.1523x; 1.0167x over previous
//
#include <hip/hip_runtime.h>
#include <math.h>

#define LL 4096
#define CC 128
#define SS 64
#define CLEN 32    // steps per chunk (wave)
#define GW 8       // chunks (waves) per group/block
#define NG 16      // groups; NG*GW*CLEN = LL
#define CS 8192    // CC*SS
#define LOG2E 1.44269504088896f

// ---------------- kernel 1: projections (B, Cm, dtT) + xT (R12 verbatim) ----
__global__ __launch_bounds__(256) void k_proj(
    const float* __restrict__ x,
    const float* __restrict__ Bk, const float* __restrict__ Bb,
    const float* __restrict__ Ck, const float* __restrict__ Cb,
    const float* __restrict__ Dk, const float* __restrict__ Db,
    float* __restrict__ Bmat, float* __restrict__ Cmat,
    float* __restrict__ DTmT, float* __restrict__ xT)
{
    __shared__ float xs[CC][20];
    const int r0 = blockIdx.x * 16;
    const int t = threadIdx.x;
    {
        const int r = t >> 4, k8 = (t & 15) * 8;
        const float4 v0 = *(const float4*)&x[(r0 + r) * CC + k8];
        const float4 v1 = *(const float4*)&x[(r0 + r) * CC + k8 + 4];
        xs[k8+0][r] = v0.x; xs[k8+1][r] = v0.y; xs[k8+2][r] = v0.z; xs[k8+3][r] = v0.w;
        xs[k8+4][r] = v1.x; xs[k8+5][r] = v1.y; xs[k8+6][r] = v1.z; xs[k8+7][r] = v1.w;
    }
    __syncthreads();
    {   // emit x transposed [C][L]
        const int k = t >> 1, half = (t & 1) * 8;
        const float4 a = *(const float4*)&xs[k][half];
        const float4 b = *(const float4*)&xs[k][half + 4];
        *(float4*)&xT[k * LL + r0 + half]     = a;
        *(float4*)&xT[k * LL + r0 + half + 4] = b;
    }
    const int tc = t & 63, tr = t >> 6;
    const float* Wb; int wstride, wo;
    if (tc < 16)      { Wb = Bk; wstride = SS; wo = 4 * tc; }
    else if (tc < 32) { Wb = Ck; wstride = SS; wo = 4 * tc - 64; }
    else              { Wb = Dk; wstride = CC; wo = 4 * tc - 128; }
    float acc[4][4];
#pragma unroll
    for (int r = 0; r < 4; ++r)
#pragma unroll
        for (int j = 0; j < 4; ++j) acc[r][j] = 0.0f;
    for (int k = 0; k < CC; ++k) {
        const float4 wq = *(const float4*)(Wb + k * wstride + wo);
        const float4 xq = *(const float4*)&xs[k][4 * tr];
        const float wv[4] = {wq.x, wq.y, wq.z, wq.w};
        const float xv[4] = {xq.x, xq.y, xq.z, xq.w};
#pragma unroll
        for (int r = 0; r < 4; ++r)
#pragma unroll
            for (int j = 0; j < 4; ++j) acc[r][j] = fmaf(xv[r], wv[j], acc[r][j]);
    }
    const int rb = r0 + 4 * tr;
    if (tc < 32) {
        const float* bb = (tc < 16) ? Bb : Cb;
        const float add = (tc < 16) ? 1.0f : 0.0f;
        float bias[4];
#pragma unroll
        for (int j = 0; j < 4; ++j) bias[j] = add + bb[wo + j];
        float* dst = (tc < 16) ? Bmat : Cmat;
#pragma unroll
        for (int r = 0; r < 4; ++r) {
            const float4 o = make_float4(acc[r][0] + bias[0], acc[r][1] + bias[1],
                                         acc[r][2] + bias[2], acc[r][3] + bias[3]);
            *(float4*)&dst[(rb + r) * SS + wo] = o;
        }
    } else {
#pragma unroll
        for (int j = 0; j < 4; ++j) {
            const float bj = Db[wo + j] + 0.000244140625f;
            float sp[4];
#pragma unroll
            for (int r = 0; r < 4; ++r) {
                const float z = acc[r][j] + bj;
                sp[r] = fmaxf(z, 0.0f) + log1pf(__expf(-fabsf(z)));
            }
            *(float4*)&DTmT[(wo + j) * LL + rb] = make_float4(sp[0], sp[1], sp[2], sp[3]);
        }
    }
}

// ------- kernel 2: group aggregates (R12 verbatim) -------
// block = (c, g): 2048 blocks x 512 thr = 8 waves = 8 chunks of group g. lane = s.
__global__ __launch_bounds__(512, 4) void k_sweep1(
    const float* __restrict__ xT, const float* __restrict__ A_log,
    const float* __restrict__ Bmat, const float* __restrict__ DTmT,
    float2* __restrict__ GaGu)
{
    __shared__ float2 agg[GW][SS];
    const int lane = threadIdx.x & 63;
    const int w = __builtin_amdgcn_readfirstlane(threadIdx.x >> 6);
    const int c = blockIdx.x >> 4;          // SGPR
    const int g = blockIdx.x & (NG - 1);    // SGPR
    const int j = c * SS + lane;
    const float A = -__expf(A_log[j]);
    const float A2 = A * LOG2E;             // At = 2^(A2*dt)
    const float invA = 1.0f / A;
    const int l0 = (g * GW + w) * CLEN;
    const float* dtp = DTmT + c * LL + l0;  // uniform + contiguous -> s_load batches
    const float* xp  = xT   + c * LL + l0;
    const float* Bp  = Bmat + l0 * SS + lane;
    float ap = 1.0f, uc = 0.0f;
#pragma unroll
    for (int i = 0; i < CLEN; ++i) {
        const float At = __builtin_amdgcn_exp2f(A2 * dtp[i]);
        const float u  = (At - 1.0f) * invA * (Bp[i * SS] * xp[i]);
        ap *= At;
        uc = fmaf(At, uc, u);
    }
    agg[w][lane] = make_float2(ap, uc);
    __syncthreads();
    if (w == 0) {   // compose 8 chunks in time order -> group aggregate
        float ga = 1.0f, gu = 0.0f;
#pragma unroll
        for (int k = 0; k < GW; ++k) {
            const float2 t = agg[k][lane];
            gu = fmaf(t.x, gu, t.y);
            ga *= t.x;
        }
        GaGu[g * CS + j] = make_float2(ga, gu);
    }
}

// ------- kernel 3: wave0-prologue + reg-cached rewalk + emit -------
// __launch_bounds__(512) WITHOUT min-wave clamp: lets the allocator use up to
// 256 VGPR so at[32]/uu[32]/ggr[30] genuinely live in registers (no scratch).
__global__ __launch_bounds__(512) void k_emit(
    const float* __restrict__ xT, const float* __restrict__ A_log,
    const float* __restrict__ Bmat, const float* __restrict__ Cmat,
    const float* __restrict__ DTmT,
    const float2* __restrict__ GaGu,
    float* __restrict__ y)
{
    __shared__ float2 agg[GW][SS];
    __shared__ float hgs[SS];
    const int lane = threadIdx.x & 63;
    const int w = __builtin_amdgcn_readfirstlane(threadIdx.x >> 6);
    const int c = blockIdx.x >> 4;          // SGPR
    const int g = blockIdx.x & (NG - 1);    // SGPR
    const int j = c * SS + lane;
    const float A = -__expf(A_log[j]);
    const float A2 = A * LOG2E;
    const float invA = 1.0f / A;
    // cross-group exclusive prefix: wave 0 only (identical across waves)
    if (w == 0) {
        float hg = 0.0f;
        float2 ggr[NG - 1];
#pragma unroll
        for (int gg = 0; gg < NG - 1; ++gg) ggr[gg] = GaGu[gg * CS + j];
#pragma unroll
        for (int gg = 0; gg < NG - 1; ++gg)
            hg = (gg < g) ? fmaf(ggr[gg].x, hg, ggr[gg].y) : hg;
        hgs[lane] = hg;
    }
    const int l0 = (g * GW + w) * CLEN;
    const float* dtp = DTmT + c * LL + l0;
    const float* xp  = xT   + c * LL + l0;
    const float* Bp  = Bmat + l0 * SS + lane;
    const float* Cp  = Cmat + l0 * SS + lane;
    // pass 1: chunk aggregate, caching at[] / uu[] in registers
    float at[CLEN], uu[CLEN];
    {
        float ap = 1.0f, uc = 0.0f;
#pragma unroll
        for (int i = 0; i < CLEN; ++i) {
            at[i] = __builtin_amdgcn_exp2f(A2 * dtp[i]);
            uu[i] = (at[i] - 1.0f) * invA * (Bp[i * SS] * xp[i]);
            ap *= at[i];
            uc = fmaf(at[i], uc, uu[i]);
        }
        agg[w][lane] = make_float2(ap, uc);
    }
    __syncthreads();
    const float hg = hgs[lane];
    // in-block exclusive prefix over chunks 0..w-1 (trip count wave-uniform)
    float ea = 1.0f, eu = 0.0f;
    for (int k = 0; k < w; ++k) {
        const float2 t = agg[k][lane];
        eu = fmaf(t.x, eu, t.y);
        ea *= t.x;
    }
    float h = fmaf(ea, hg, eu);
    // pass 2: rewalk from registers; uu[] becomes p[]
#pragma unroll
    for (int i = 0; i < CLEN; ++i) {
        h = fmaf(at[i], h, uu[i]);
        uu[i] = Cp[i * SS] * h;
    }
    // 32-row x 64-lane register-halving transpose-reduce
#pragma unroll
    for (int k = 0; k < 5; ++k) {
        const int d = 1 << k;
        const bool hi = (lane & d) != 0;
#pragma unroll
        for (int i2 = 0; i2 < (CLEN >> (k + 1)); ++i2) {
            const float a = uu[2 * i2], b = uu[2 * i2 + 1];
            const float send = hi ? a : b;
            const float t = __shfl_xor(send, d, 64);
            uu[i2] = (hi ? b : a) + t;
        }
    }
    const float t = __shfl_xor(uu[0], 32, 64);
    const float yv = uu[0] + t;
    if (lane < 32) y[(l0 + lane) * CC + c] = yv;
}

extern "C" void kernel_launch(void* const* d_in, const int* in_sizes, int n_in,
                              void* d_out, int out_size, void* d_ws, size_t ws_size,
                              hipStream_t stream)
{
    const float* x  = (const float*)d_in[0];
    const float* Al = (const float*)d_in[1];
    const float* Bk = (const float*)d_in[2];
    const float* Bb = (const float*)d_in[3];
    const float* Ck = (const float*)d_in[4];
    const float* Cb = (const float*)d_in[5];
    const float* Dk = (const float*)d_in[6];
    const float* Db = (const float*)d_in[7];
    float* y  = (float*)d_out;
    float* ws = (float*)d_ws;

    float*  Bmat = ws;                        // [L][S]   1 MB
    float*  Cmat = Bmat + LL * SS;            // [L][S]   1 MB
    float*  DTmT = Cmat + LL * SS;            // [C][L]   2 MB
    float*  xT   = DTmT + CC * LL;            // [C][L]   2 MB
    float2* GaGu = (float2*)(xT + CC * LL);   // [NG][CS] 1 MB

    k_proj  <<<LL / 16, 256, 0, stream>>>(x, Bk, Bb, Ck, Cb, Dk, Db, Bmat, Cmat, DTmT, xT);
    k_sweep1<<<CC * NG, 512, 0, stream>>>(xT, Al, Bmat, DTmT, GaGu);
    k_emit  <<<CC * NG, 512, 0, stream>>>(xT, Al, Bmat, Cmat, DTmT, GaGu, y);
}